// Round 4
// baseline (259.620 us; speedup 1.0000x reference)
//
#include <hip/hip_runtime.h>

// IndexNSW R8: 4 CUs per query. The storage-fill phase is per-CU
// line-fill-parallelism bound (~27 lines in flight/CU, 256 lines/step => ~4
// serialized latency rounds; proven by R4==R7 under 8x transaction-count
// change). Fix: split the 32 rows across 4 blocks (8 rows = 64 lines each,
// ~1 round), replicate ALL search state (visited/expanded/pool/merge/pick
// are deterministic => replicas never diverge), and broadcast only the 32
// (d,id) candidates per step.
//
// Comms: one u64 per candidate slot: d_bits<<32 | id<<7 | step_tag.
//  - relaxed AGENT-scope atomics only (coherence-point ops): no fences, no
//    cache invalidates (keeps storage L2/L3-resident), XCD-safe.
//  - self-validating: consumer spins until tag==s+1, then d/id are from the
//    same word => no release/acquire pairing needed.
//  - double-buffered by step parity: overwrite needs a 2-full-step
//    straggler, impossible (each step is a rendezvous on all 32 words).
//  - co-residency: 256 blocks x 1 wave << 8192-wave capacity => all blocks
//    resident regardless of packing; no dispatch-order assumption.
//
// Numerics: per-row distance = R4's exact 2-lane/32-chunk fmaf chain +
// cross-half shfl; merge key/rank/scatter/pick byte-identical to R4 =>
// bit-identical trajectory and output (absmax 0.0 preserved).

#define DIMS    256
#define RDEG    32
#define EFPOOL  32
#define KOUT    10
#define NWORDS  3125     // ceil(100000 / 32)
#define INF_D   1e30f
#define NSPLIT  4        // blocks (CUs) per query
#define ROWS_PB 8        // RDEG / NSPLIT

typedef unsigned long long u64;

__global__ __launch_bounds__(64, 1) void nsw_coop_kernel(
    const float* __restrict__ query,    // [B, 256]
    const float* __restrict__ storage,  // [N, 256]
    const int*   __restrict__ graph,    // [N, 32]
    const int*   __restrict__ initial,  // [B, 32]
    u64*         __restrict__ cand,     // [2][B][32] tagged (d,id) words (zeroed)
    float*       __restrict__ out,      // [B*10 ids as float][B*10 dists]
    int B)
{
    __shared__ unsigned int visited[NWORDS];
    __shared__ unsigned int expanded[NWORDS];
    __shared__ float4 qsh[DIMS / 4];            // query row, 64 float4
    __shared__ u64    keys[64];                 // merge keys
    __shared__ float  sc_d[EFPOOL];             // merge scatter scratch
    __shared__ int    sc_id[EFPOOL];

    const int l     = threadIdx.x;              // 0..63
    const int q     = blockIdx.x % B;           // query
    const int g     = blockIdx.x / B;           // slice 0..3 (same-XCD stride)
    const int nb    = l & 31;                   // pool slot / cand slot owned
    const int half  = l >> 5;                   // 128-dim half for distance
    const bool dlane = (nb < ROWS_PB);          // lanes 0-7 & 32-39: distance duty
    const int slot  = g * ROWS_PB + (nb & 7);   // my row's global cand slot

    for (int i = l; i < NWORDS; i += 64) { visited[i] = 0u; expanded[i] = 0u; }

    // stage query row to LDS (coalesced: lane l -> float4 l)
    qsh[l] = reinterpret_cast<const float4*>(query + (size_t)q * DIMS)[l];

    float pool_d  = INF_D;   // dummy pool; first merge sorts the real entries in
    int   pool_id = 0;
    int   u       = 0;       // node expanded this step (replicated)

    for (int s = 0; s <= EFPOOL; ++s) {        // s==0: initial pool, then 32 steps
        const unsigned want = (unsigned)(s + 1);
        u64* cbuf = cand + ((size_t)(s & 1) * B + q) * EFPOOL;

        // mark previous u expanded (sole writer; precedes this step's pick)
        if (s > 0 && l == 0) expanded[u >> 5] |= 1u << (u & 31);

        // ---- own row ids for this step ----
        int myid = 0;
        if (dlane)
            myid = (s == 0) ? initial[q * EFPOOL + slot]
                            : graph[(size_t)u * RDEG + slot];

        // step-0: every replica marks ALL 32 initial ids (reference inits
        // visited at init ids before the scan)
        if (s == 0 && l < 32) {
            int iid = initial[q * EFPOOL + l];
            atomicOr(&visited[iid >> 5], 1u << (iid & 31));
        }

        // fresh check against pre-step-s visited state (marking of this
        // step's 32 ids happens later, in the receive phase: program order)
        bool fresh = true;
        if (s > 0 && dlane)
            fresh = !((visited[myid >> 5] >> (myid & 31)) & 1u);

        // ---- distance: R4's EXACT per-row chain (2 lanes x 32 chunks) ----
        float nd_pub = INF_D;
        if (dlane) {
            const float4* sp = reinterpret_cast<const float4*>(
                storage + (size_t)myid * DIMS) + half * 32;
            float4 r[32];
            #pragma unroll
            for (int j = 0; j < 32; ++j) r[j] = sp[j];   // 64 lines in flight
            float a0 = 0.f, a1 = 0.f, a2 = 0.f, a3 = 0.f;
            #pragma unroll
            for (int j = 0; j < 32; ++j) {
                float4 qv = qsh[half * 32 + j];
                float d0 = r[j].x - qv.x; a0 = fmaf(d0, d0, a0);
                float d1 = r[j].y - qv.y; a1 = fmaf(d1, d1, a1);
                float d2 = r[j].z - qv.z; a2 = fmaf(d2, d2, a2);
                float d3 = r[j].w - qv.w; a3 = fmaf(d3, d3, a3);
            }
            float part = (a0 + a1) + (a2 + a3);
            float dmine = part + __shfl_xor(part, 32, 64);   // halves share row
            nd_pub = fresh ? dmine : INF_D;
        }

        // ---- publish own 8 rows (half0 lanes): self-validating word ----
        if (l < ROWS_PB) {
            u64 w = ((u64)__float_as_uint(nd_pub) << 32)
                  | ((u64)(unsigned)myid << 7) | (u64)want;
            __hip_atomic_store(&cbuf[slot], w, __ATOMIC_RELAXED,
                               __HIP_MEMORY_SCOPE_AGENT);
        }

        // local broadcast of own-block rows (reconverged shfl: sources active)
        float loc_d = __shfl(nd_pub, nb & 7, 64);
        int   loc_i = __shfl(myid,  nb & 7, 64);

        // ---- receive all 32 candidates on lanes >= 32 ----
        float cd = INF_D; int cid = 0;
        if (l >= 32) {
            if ((nb >> 3) == g) {            // own block's slot: no round trip
                cd  = loc_d;
                cid = loc_i;
            } else {                          // remote: spin on tag
                u64 w;
                do {
                    w = __hip_atomic_load(&cbuf[nb], __ATOMIC_RELAXED,
                                          __HIP_MEMORY_SCOPE_AGENT);
                } while ((unsigned)(w & 0x7Fu) != want);
                cd  = __uint_as_float((unsigned)(w >> 32));
                cid = (int)((w >> 7) & 0x1FFFFu);
            }
            // mark visited for ALL 32 step-s ids (replicated state update)
            atomicOr(&visited[cid >> 5], 1u << (cid & 31));
        }

        // ---- merge: 64 concat elems -> sorted top-32 (byte-identical R4) ----
        {
            float ed  = (l >= 32) ? cd  : pool_d;
            int   eid = (l >= 32) ? cid : pool_id;
            u64 key = ((u64)__float_as_uint(ed) << 6) | (unsigned)l;
            keys[l] = key;
            int rank = 0;
            #pragma unroll
            for (int j = 0; j < 64; ++j)            // same addr all lanes: broadcast
                rank += (keys[j] < key) ? 1 : 0;
            if (rank < EFPOOL) { sc_d[rank] = ed; sc_id[rank] = eid; }  // ranks unique
            pool_d  = sc_d[nb];                     // in-order DS: no barrier
            pool_id = sc_id[nb];
        }

        // ---- pick next u = first unexpanded slot (replicated) ----
        if (s < EFPOOL) {
            bool unexp = !((expanded[pool_id >> 5] >> (pool_id & 31)) & 1u);
            u64 bm = __ballot(unexp && (l < 32));
            int sl = (bm == 0ull) ? 0 : (__ffsll(bm) - 1);
            u = sc_id[sl];                          // uniform slot: broadcast read
        }
    }

    // ---- output (slice 0 only): pool sorted ascending ----
    if (g == 0 && l < KOUT) {
        out[q * KOUT + l]            = (float)pool_id;
        out[B * KOUT + q * KOUT + l] = pool_d;
    }
}

extern "C" void kernel_launch(void* const* d_in, const int* in_sizes, int n_in,
                              void* d_out, int out_size, void* d_ws, size_t ws_size,
                              hipStream_t stream) {
    const float* query   = (const float*)d_in[0];
    const float* storage = (const float*)d_in[1];
    const int*   graph   = (const int*)d_in[2];
    const int*   initial = (const int*)d_in[3];
    float* out = (float*)d_out;

    const int B = in_sizes[0] / DIMS;   // 64

    // zero the tagged-candidate mailbox (tags restart at 1 each launch)
    const size_t cand_bytes = (size_t)2 * B * EFPOOL * sizeof(u64);
    hipMemsetAsync(d_ws, 0, cand_bytes, stream);

    nsw_coop_kernel<<<B * NSPLIT, 64, 0, stream>>>(
        query, storage, graph, initial, (u64*)d_ws, out, B);
}

// Round 5
// 228.220 us; speedup vs baseline: 1.1376x; 1.1376x over previous
//
#include <hip/hip_runtime.h>

// IndexNSW R9: R4 + exact dual-candidate speculation => software-pipelined
// step. One WAVE per query (B=64 blocks x 64 threads), zero barriers.
//
// R8 (4-CU split, 127us) abandoned: agent-scope rendezvous ~3-4Kcy/step
// (coherence-point polls + max-of-4-replica skew) > fill savings.
//
// R9 idea: R4's step = fill(3800cy) + SERIAL tail {dist 400, merge 800,
// pick 100, graph 900}. The true next pick is EXACTLY
//   min by (d, concat-idx) of  (best unexpanded old-pool slot)
//                           vs (best fresh new candidate)
// unless that min falls outside the merged top-32 (all-expanded corner,
// caught by verify). Both candidates are known right after the distances,
// BEFORE the merge:
//   - old cand: same ballot as the pick, computed at iteration start while
//     the fill is in flight (LDS work under fill is free - R6/R7 lesson).
//   - new cand: 6-step u64 shfl_xor min-reduce over (dbits<<6 | 32+slot),
//     exact keys => no truncation mispredicts (unlike R5/R6).
// graph[u_spec] is issued before the merge (vmcnt domain; merge's lgkmcnt
// waits don't drain it), so merge+pick run under the graph latency, and the
// next step's storage fill issues the moment graph data lands. Steady-state
// step ~= dist + spec + max(graph, merge) + fill ~= 5.3Kcy vs 7.5Kcy.
//
// Numerics: dist fmaf chain, merge key/rank/scatter, pick, and output are
// byte-identical to R4 => bit-identical trajectory (absmax 0.0 preserved).
// Merge key = (f32 bits of d)<<6 | concat idx: d>=0 so u64 order ==
// (d, idx) lexicographic == lax.top_k stable order, incl. duplicate-id ties.

#define DIMS   256
#define RDEG   32
#define EFPOOL 32
#define KOUT   10
#define NWORDS 3125     // ceil(100000 / 32)
#define INF_D  1e30f

typedef unsigned long long u64;

__global__ __launch_bounds__(64, 1) void nsw_wave_kernel(
    const float* __restrict__ query,    // [B, 256]
    const float* __restrict__ storage,  // [N, 256]
    const int*   __restrict__ graph,    // [N, 32]
    const int*   __restrict__ initial,  // [B, 32]
    float*       __restrict__ out,      // [B*10 ids as float][B*10 dists]
    int B)
{
    __shared__ unsigned int visited[NWORDS];
    __shared__ unsigned int expanded[NWORDS];
    __shared__ float4 qsh[DIMS / 4];            // query row, 64 float4
    __shared__ u64    keys[64];                 // merge keys
    __shared__ float  sc_d[EFPOOL];             // merge scatter scratch
    __shared__ int    sc_id[EFPOOL];

    const int l    = threadIdx.x;   // 0..63
    const int b    = blockIdx.x;
    const int nb   = l & 31;        // neighbor / pool slot owned (dup across halves)
    const int half = l >> 5;        // which 128-dim half this lane covers

    for (int i = l; i < NWORDS; i += 64) { visited[i] = 0u; expanded[i] = 0u; }

    // stage query row to LDS (coalesced: lane l -> float4 l)
    qsh[l] = reinterpret_cast<const float4*>(query + (size_t)b * DIMS)[l];

    float pool_d  = INF_D;   // dummy pool; first merge sorts the real entries in
    int   pool_id = 0;
    int   u       = 0;       // node expanded this step (valid from s==1)
    int   nbid    = initial[b * EFPOOL + nb];   // per-lane id of slot nb

    // reference marks all initial ids visited before the scan
    if (l < 32) atomicOr(&visited[nbid >> 5], 1u << (nbid & 31));

    // ---- prologue: issue fill for the initial pool ----
    float4 r[32];
    {
        const float4* sp = reinterpret_cast<const float4*>(
            storage + (size_t)nbid * DIMS) + half * 32;
        #pragma unroll
        for (int j = 0; j < 32; ++j) r[j] = sp[j];
    }

    for (int s = 0; s <= EFPOOL; ++s) {        // s==0: initial pool, then 32 steps
        // ---- work hidden under the in-flight fill (LDS only) ----
        // mark previous u expanded (sole writer; in-wave DS program order
        // makes it visible to the old-cand reads below)
        if (s > 0 && l == 0) expanded[u >> 5] |= 1u << (u & 31);

        // visited bookkeeping for this step's ids (read-all precedes OR:
        // duplicates all see pre-update state, same as the reference)
        bool fresh = true;
        if (s > 0) {
            unsigned vw = visited[nbid >> 5];
            fresh = !((vw >> (nbid & 31)) & 1u);
            if ((l < 32) && fresh) atomicOr(&visited[nbid >> 5], 1u << (nbid & 31));
        }

        // old candidate: first unexpanded slot of the CURRENT pool (pool is
        // sorted ascending). Uses expanded[] per-slot => duplicate-id safe.
        bool ounexp = !((expanded[pool_id >> 5] >> (pool_id & 31)) & 1u);
        u64  obm    = __ballot(ounexp && (l < 32));
        int  oslot  = (obm == 0ull) ? 0 : (__ffsll(obm) - 1);
        float old_d = __shfl(pool_d,  oslot, 64);
        int   old_id= __shfl(pool_id, oslot, 64);
        bool  old_ok= (obm != 0ull);

        // ---- distance: R4's EXACT chain (compiler waits the fill here) ----
        float a0 = 0.f, a1 = 0.f, a2 = 0.f, a3 = 0.f;
        #pragma unroll
        for (int j = 0; j < 32; ++j) {
            float4 q = qsh[half * 32 + j];
            float d0 = r[j].x - q.x; a0 = fmaf(d0, d0, a0);
            float d1 = r[j].y - q.y; a1 = fmaf(d1, d1, a1);
            float d2 = r[j].z - q.z; a2 = fmaf(d2, d2, a2);
            float d3 = r[j].w - q.w; a3 = fmaf(d3, d3, a3);
        }
        float part = (a0 + a1) + (a2 + a3);
        float d  = part + __shfl_xor(part, 32, 64);   // halves share a row
        float nd = fresh ? d : INF_D;

        int nnbid = nbid;
        int uspec = 0;
        if (s < EFPOOL) {
            // new candidate: exact min over fresh news by (dbits<<6 | 32+slot)
            u64 nk = fresh ? (((u64)__float_as_uint(nd) << 6) | (u64)(32 + nb))
                           : ~0ull;
            #pragma unroll
            for (int m = 1; m < 64; m <<= 1) {
                u64 o = __shfl_xor(nk, m, 64);
                nk = (o < nk) ? o : nk;
            }
            int new_id = __shfl(nbid, ((int)(nk & 63) - 32) & 31, 64);
            u64 ok = old_ok ? (((u64)__float_as_uint(old_d) << 6) | (u64)oslot)
                            : ~0ull;
            // exact union order: old wins ties (lower concat idx)
            uspec = (ok < nk) ? old_id : new_id;
            // speculative graph prefetch (vmcnt domain: merge's lgkmcnt waits
            // below do not drain it)
            nnbid = graph[(size_t)uspec * RDEG + nb];
        }

        // ---- merge: 64 concat elems -> sorted top-32 (byte-identical R4) ----
        {
            float ed  = half ? nd   : pool_d;
            int   eid = half ? nbid : pool_id;
            u64 key = ((u64)__float_as_uint(ed) << 6) | (unsigned)l;
            keys[l] = key;
            int rank = 0;
            #pragma unroll
            for (int j = 0; j < 64; ++j)            // same addr all lanes: broadcast
                rank += (keys[j] < key) ? 1 : 0;
            if (rank < EFPOOL) { sc_d[rank] = ed; sc_id[rank] = eid; }  // ranks unique
            pool_d  = sc_d[nb];                     // in-order DS: no barrier
            pool_id = sc_id[nb];
        }

        // ---- true pick + verify; issue next step's fill ----
        if (s < EFPOOL) {
            bool unexp = !((expanded[pool_id >> 5] >> (pool_id & 31)) & 1u);
            u64 bm = __ballot(unexp && (l < 32));
            int slot = (bm == 0ull) ? 0 : (__ffsll(bm) - 1);
            int utrue = sc_id[slot];                // uniform slot: broadcast read
            int ut = __builtin_amdgcn_readfirstlane(utrue);
            int us = __builtin_amdgcn_readfirstlane(uspec);
            if (ut != us)                            // all-expanded corner: reload
                nnbid = graph[(size_t)utrue * RDEG + nb];
            u    = utrue;
            nbid = nnbid;                            // vmcnt wait lands here
            const float4* sp = reinterpret_cast<const float4*>(
                storage + (size_t)nbid * DIMS) + half * 32;
            #pragma unroll
            for (int j = 0; j < 32; ++j) r[j] = sp[j];   // next fill in flight
        }
    }

    // ---- output: pool sorted ascending; ids as float (exact < 2^24), then dists ----
    if (l < KOUT) {
        out[b * KOUT + l]            = (float)pool_id;
        out[B * KOUT + b * KOUT + l] = pool_d;
    }
}

extern "C" void kernel_launch(void* const* d_in, const int* in_sizes, int n_in,
                              void* d_out, int out_size, void* d_ws, size_t ws_size,
                              hipStream_t stream) {
    const float* query   = (const float*)d_in[0];
    const float* storage = (const float*)d_in[1];
    const int*   graph   = (const int*)d_in[2];
    const int*   initial = (const int*)d_in[3];
    float* out = (float*)d_out;

    const int B = in_sizes[0] / DIMS;   // 64

    nsw_wave_kernel<<<B, 64, 0, stream>>>(query, storage, graph, initial, out, B);
}